// Round 1
// baseline (1224.772 us; speedup 1.0000x reference)
//
#include <hip/hip_runtime.h>
#include <hip/hip_bf16.h>

typedef unsigned int  u32;
typedef unsigned short u16;
typedef unsigned char u8;
typedef __attribute__((ext_vector_type(8))) short  short8;   // 8 bf16 codes (4 VGPRs)
typedef __attribute__((ext_vector_type(8))) u16    ushort8;
typedef __attribute__((ext_vector_type(4))) float  f32x4;

#define DEVI __device__ __forceinline__

constexpr int CB = 16;    // batch
constexpr int CC = 128;   // channels
constexpr int CW = 8;     // width
constexpr int CK = 5;     // kernel taps (dilation 2)
constexpr int T0g = 2048, T1g = 2040, T2g = 2032, T3g = 2024, T4g = 2016;

// ws layout:
//  hdr u32[0]=max_x [1]=max_h1 [2]=max_r2 [3]=qrmax [4]=max_h3 [5]=max_r4 ; f32 slots [6]=s_w1 [7]=s_w2
//  +512      : wlay1 (5*128*128 bf16 codes, fragment-ordered) 163840 B
//  +512+160K : wlay2
//  +512KiB   : qT   (bf16 codes, [b][n][ci])   67,108,864 B
//  +512K+64M : hbuf (fp32, [b][co][t][w])     134,217,728 B
//  + ...     : rbuf (u8, [b][n][c])            33,554,432 B
// total ~225 MB

DEVI float wred_max(float m){
  #pragma unroll
  for (int off = 32; off; off >>= 1) m = fmaxf(m, __shfl_down(m, off));
  return m;
}
DEVI u32 wred_maxu(u32 m){
  #pragma unroll
  for (int off = 32; off; off >>= 1){ u32 o = __shfl_down(m, off); m = m > o ? m : o; }
  return m;
}
DEVI float act_scale(u32 bits){ return fmaxf(__uint_as_float(bits) / 127.0f, 1e-8f); }
// exact for small integers (|q|<=255 has >=8 trailing zero mantissa bits)
DEVI u16 f2bf(float q){ return (u16)(__float_as_uint(q) >> 16); }

// ---------------- abs-max over x ----------------
__global__ void k_absmax(const float* __restrict__ x, int n4, u32* __restrict__ slot){
  int gid = blockIdx.x * blockDim.x + threadIdx.x;
  int nth = gridDim.x * blockDim.x;
  const float4* x4 = (const float4*)x;
  float m = 0.f;
  for (int i = gid; i < n4; i += nth){
    float4 v = x4[i];
    m = fmaxf(m, fmaxf(fmaxf(fabsf(v.x), fabsf(v.y)), fmaxf(fabsf(v.z), fabsf(v.w))));
  }
  m = wred_max(m);
  if ((threadIdx.x & 63) == 0 && m > 0.f) atomicMax(slot, __float_as_uint(m));
}

// ---------------- weight quant + fragment-order shuffle ----------------
// wlay linear index = (((kk*4+st)*8 + cot)*64 + lane)*8 + j
//   holds q_w for co = cot*16 + (lane&15), ci = st*32 + (lane>>4)*8 + j  (A-frag order)
__global__ void k_quant_w(const float* __restrict__ w, u16* __restrict__ wlay, float* __restrict__ s_slot){
  __shared__ float red[16];
  int tid = threadIdx.x; // 1024
  float m = 0.f;
  for (int i = tid; i < CC*CC*CK; i += 1024) m = fmaxf(m, fabsf(w[i]));
  m = wred_max(m);
  if ((tid & 63) == 0) red[tid >> 6] = m;
  __syncthreads();
  if (tid == 0){
    float mm = 0.f;
    for (int i = 0; i < 16; i++) mm = fmaxf(mm, red[i]);
    red[0] = fmaxf(mm / 127.0f, 1e-8f);
    *s_slot = red[0];
  }
  __syncthreads();
  float s = red[0];
  for (int i = tid; i < CC*CC*CK; i += 1024){
    int j = i & 7, lane = (i >> 3) & 63, cot = (i >> 9) & 7, st = (i >> 12) & 3, kk = i >> 14;
    int co = cot*16 + (lane & 15), ci = st*32 + (lane >> 4)*8 + j;
    float q = rintf(w[(co*CC + ci)*CK + kk] / s);
    q = fminf(fmaxf(q, -127.f), 127.f);
    wlay[i] = f2bf(q);
  }
}

// ---------------- quantize + transpose: fp32 [b][c][N] -> bf16 codes [b][n][c] ----------------
// strided scalar reads stay L1-resident (per-block working set = 128c x 64n x 4B = 32 KiB)
__global__ void k_quantT(const float* __restrict__ h, u16* __restrict__ qT,
                         const u32* __restrict__ slot, int N){
  int b = blockIdx.y;
  int n0 = blockIdx.x * 64;
  float s = act_scale(*slot);
  const float* hb = h + (size_t)b * CC * N;
  u16* qb = qT + (size_t)b * N * CC;
  for (int o = threadIdx.x; o < 64*16; o += 256){
    int n = n0 + (o >> 4), cch = (o & 15) * 8;
    ushort8 pk;
    #pragma unroll
    for (int j = 0; j < 8; j++){
      float v = hb[(size_t)(cch + j) * N + n];
      float q = fminf(fmaxf(rintf(v / s), -128.f), 127.f);
      pk[j] = f2bf(q);
    }
    *(ushort8*)(qb + (size_t)n * CC + cch) = pk;
  }
}

// ---------------- conv + bn (+ fused abs/relu max) ----------------
// qT: [b][n][128] bf16 codes. wlay: fragment-ordered codes. hout: [b][co][Tout*8] fp32.
// LDS tile: 192 window-rows (24 t x 8 w) x 128 ci, chunk-XOR swizzled:
//   physical 16B-chunk p at row n holds logical chunk p^(n&15)  (inverse-swizzled source, rule #21)
__global__ __launch_bounds__(256)
void k_conv(const u16* __restrict__ qT, const u16* __restrict__ wlay,
            const float* __restrict__ gg, const float* __restrict__ bbt,
            const float* __restrict__ mmu, const float* __restrict__ vvar,
            float* __restrict__ hout,
            const u32* __restrict__ slotA, const u32* __restrict__ slotB, int smode,
            const float* __restrict__ sw_slot,
            u32* __restrict__ omax, int relu_mode,
            int Tin, int Tout)
{
  __shared__ __align__(16) short lds[192*128];
  __shared__ float s_alpha[CC], s_beta[CC], s_red[4];
  int tid = threadIdx.x;
  int b = blockIdx.y, t0 = blockIdx.x * 16;

  if (tid < CC){
    float inv = gg[tid] / sqrtf(vvar[tid] + 1e-5f);
    float s_in;
    if (smode == 0){
      s_in = act_scale(*slotA);
    } else { // nested: relu-uint8 output re-quantized by quant_act_int8
      float sr = fmaxf(__uint_as_float(*slotA) / 255.0f, 1e-8f);
      float hm = (float)(*slotB) * sr;          // max|h| = q_rmax * s_r
      s_in = fmaxf(hm / 127.0f, 1e-8f);
    }
    s_alpha[tid] = s_in * (*sw_slot) * inv;
    s_beta[tid]  = bbt[tid] - mmu[tid] * inv;
  }

  // stage input window via global_load_lds (width 16), swizzled source
  const u16* qb = qT + (size_t)b * Tin * CW * CC;
  int NT = Tin * CW;
  for (int r = 0; r < 12; r++){
    int ck = r*256 + tid;          // 0..3071
    int n  = ck >> 4;              // window row 0..191
    int p  = ck & 15;              // physical chunk
    int src_n = t0*CW + n;
    if (src_n >= NT) src_n = n & 7;       // tail clamp: any valid row; garbage feeds only invalid cols
    size_t srcoff = (size_t)src_n * CC + (size_t)((p ^ (n & 15)) * 8);
    __builtin_amdgcn_global_load_lds(
        (const __attribute__((address_space(1))) u32*)(qb + srcoff),
        (__attribute__((address_space(3))) u32*)&lds[ck*8], 16, 0, 0);
  }
  __syncthreads();

  int lane = tid & 63, wv = tid >> 6;
  int wr = wv >> 1, wc = wv & 1;           // 2x2 waves: 64co x 64n each
  int l15 = lane & 15, l4 = lane >> 4;

  f32x4 acc[4][4] = {};
  const short8* wb8 = (const short8*)wlay;

  for (int kk = 0; kk < CK; kk++){
    for (int st = 0; st < 4; st++){
      short8 afr[4], bfr[4];
      #pragma unroll
      for (int i = 0; i < 4; i++)
        afr[i] = wb8[((kk*4 + st)*8 + wr*4 + i)*64 + lane];
      #pragma unroll
      for (int i = 0; i < 4; i++){
        int nw  = wc*64 + kk*16 + i*16 + l15;          // window row (n&15 == l15)
        int off = nw*128 + (((st*4 + l4) ^ l15) << 3); // swizzled read, 2-way max (free)
        bfr[i] = *(const short8*)&lds[off];
      }
      #pragma unroll
      for (int i = 0; i < 4; i++)
        #pragma unroll
        for (int j = 0; j < 4; j++)
          acc[i][j] = __builtin_amdgcn_mfma_f32_16x16x32_bf16(afr[i], bfr[j], acc[i][j], 0, 0, 0);
    }
  }

  // epilogue: scale+bn, store, fused max
  float lmax = 0.f;
  float* hb = hout + (size_t)b * CC * Tout * CW;
  int NO = Tout * CW;
  #pragma unroll
  for (int i = 0; i < 4; i++){
    #pragma unroll
    for (int j = 0; j < 4; j++){
      int n  = wc*64 + j*16 + l15;
      int tn = t0*CW + n;
      #pragma unroll
      for (int r2 = 0; r2 < 4; r2++){
        int co = wr*64 + i*16 + l4*4 + r2;   // C/D: col=lane&15, row=(lane>>4)*4+reg
        if (tn < NO){
          float v = acc[i][j][r2] * s_alpha[co] + s_beta[co];
          hb[(size_t)co * NO + tn] = v;
          lmax = fmaxf(lmax, relu_mode ? fmaxf(v, 0.f) : fabsf(v));
        }
      }
    }
  }
  lmax = wred_max(lmax);
  if (lane == 0) s_red[wv] = lmax;
  __syncthreads();
  if (tid == 0){
    float m = fmaxf(fmaxf(s_red[0], s_red[1]), fmaxf(s_red[2], s_red[3]));
    if (m > 0.f) atomicMax(omax, __float_as_uint(m));
  }
}

// ---------------- relu-quant pass A: h2 fp32 [c][N] -> q_r u8 [n][c] + qmax ----------------
__global__ void k_reluA(const float* __restrict__ h, u8* __restrict__ rq,
                        const u32* __restrict__ slotR, u32* __restrict__ qmax_slot, int N){
  int b = blockIdx.y;
  int n0 = blockIdx.x * 64;
  float s = fmaxf(__uint_as_float(*slotR) / 255.0f, 1e-8f);
  const float* hb = h + (size_t)b * CC * N;
  u8* rb = rq + (size_t)b * N * CC;
  u32 lm = 0;
  for (int o = threadIdx.x; o < 64*8; o += 256){
    int n = n0 + (o >> 3), cch = (o & 7) * 16;
    u8 __attribute__((aligned(16))) pk[16];
    #pragma unroll
    for (int j = 0; j < 16; j++){
      float v = hb[(size_t)(cch + j) * N + n];
      float q = fminf(fmaxf(rintf(fmaxf(v, 0.f) / s), 0.f), 255.f);
      u32 qi = (u32)q;
      lm = lm > qi ? lm : qi;
      pk[j] = (u8)qi;
    }
    *(int4*)(rb + (size_t)n * CC + cch) = *(const int4*)pk;
  }
  lm = wred_maxu(lm);
  if ((threadIdx.x & 63) == 0) atomicMax(qmax_slot, lm);
}

// ---------------- relu-quant pass B: q_r u8 -> nested int8 codes (bf16) ----------------
__global__ void k_passB(const u8* __restrict__ rq, u16* __restrict__ qT,
                        const u32* __restrict__ slotR, const u32* __restrict__ qmax_slot, long n8){
  float sr = fmaxf(__uint_as_float(*slotR) / 255.0f, 1e-8f);
  float s3 = fmaxf(((float)(*qmax_slot) * sr) / 127.0f, 1e-8f);
  long gid = blockIdx.x * (long)blockDim.x + threadIdx.x;
  long nth = (long)gridDim.x * blockDim.x;
  for (long i = gid; i < n8; i += nth){
    uint2 v = ((const uint2*)rq)[i];
    ushort8 pk;
    #pragma unroll
    for (int j = 0; j < 8; j++){
      u32 qr = ((j < 4 ? v.x >> (8*j) : v.y >> (8*(j-4)))) & 0xffu;
      float hv = (float)qr * sr;                     // dequantized relu-uint8 value
      float q  = fminf(fmaxf(rintf(hv / s3), -128.f), 127.f);
      pk[j] = f2bf(q);
    }
    ((ushort8*)qT)[i] = pk;
  }
}

// ---------------- final relu-quant dequantized output ----------------
__global__ void k_final(const float* __restrict__ h, float* __restrict__ out,
                        const u32* __restrict__ slotR, int n4){
  float s = fmaxf(__uint_as_float(*slotR) / 255.0f, 1e-8f);
  int gid = blockIdx.x * blockDim.x + threadIdx.x;
  int nth = gridDim.x * blockDim.x;
  const float4* h4 = (const float4*)h;
  float4* o4 = (float4*)out;
  for (int i = gid; i < n4; i += nth){
    float4 v = h4[i], r;
    r.x = fminf(fmaxf(rintf(fmaxf(v.x, 0.f) / s), 0.f), 255.f) * s;
    r.y = fminf(fmaxf(rintf(fmaxf(v.y, 0.f) / s), 0.f), 255.f) * s;
    r.z = fminf(fmaxf(rintf(fmaxf(v.z, 0.f) / s), 0.f), 255.f) * s;
    r.w = fminf(fmaxf(rintf(fmaxf(v.w, 0.f) / s), 0.f), 255.f) * s;
    o4[i] = r;
  }
}

extern "C" void kernel_launch(void* const* d_in, const int* in_sizes, int n_in,
                              void* d_out, int out_size, void* d_ws, size_t ws_size,
                              hipStream_t stream){
  const float* x  = (const float*)d_in[0];
  const float* w1 = (const float*)d_in[1];
  const float* w2 = (const float*)d_in[2];
  const float* g1 = (const float*)d_in[3];
  const float* b1 = (const float*)d_in[4];
  const float* m1 = (const float*)d_in[5];
  const float* v1 = (const float*)d_in[6];
  const float* g2 = (const float*)d_in[7];
  const float* b2 = (const float*)d_in[8];
  const float* m2 = (const float*)d_in[9];
  const float* v2 = (const float*)d_in[10];

  char* ws   = (char*)d_ws;
  u32*  hdr  = (u32*)ws;
  float* hdrf = (float*)ws;
  u16* wl1  = (u16*)(ws + 512);
  u16* wl2  = (u16*)(ws + 512 + 163840);
  u16* qT   = (u16*)(ws + (size_t)(1 << 19));
  float* hbuf = (float*)(ws + (size_t)(1 << 19) + (size_t)67108864);
  u8*  rbuf = (u8*)(ws + (size_t)(1 << 19) + (size_t)67108864 + (size_t)134217728);

  hipMemsetAsync(hdr, 0, 64, stream);   // zero max slots (ws is poisoned 0xAA each call)
  k_quant_w<<<1, 1024, 0, stream>>>(w1, wl1, &hdrf[6]);
  k_quant_w<<<1, 1024, 0, stream>>>(w2, wl2, &hdrf[7]);
  k_absmax<<<2048, 256, 0, stream>>>(x, CB*CC*T0g*CW/4, &hdr[0]);
  k_quantT<<<dim3(T0g*CW/64, CB), 256, 0, stream>>>(x, qT, &hdr[0], T0g*CW);
  // conv1: bn1, abs-max -> max_h1
  k_conv<<<dim3(128, CB), 256, 0, stream>>>(qT, wl1, g1, b1, m1, v1, hbuf,
      &hdr[0], &hdr[3], 0, &hdrf[6], &hdr[1], 0, T0g, T1g);
  k_quantT<<<dim3(T1g*CW/64, CB), 256, 0, stream>>>(hbuf, qT, &hdr[1], T1g*CW);
  // conv2: bn2, relu-max -> max_r2
  k_conv<<<dim3(127, CB), 256, 0, stream>>>(qT, wl2, g2, b2, m2, v2, hbuf,
      &hdr[1], &hdr[3], 0, &hdrf[7], &hdr[2], 1, T1g, T2g);
  k_reluA<<<dim3(T2g*CW/64, CB), 256, 0, stream>>>(hbuf, rbuf, &hdr[2], &hdr[3], T2g*CW);
  k_passB<<<2048, 256, 0, stream>>>(rbuf, qT, &hdr[2], &hdr[3], (long)CB*T2g*CW*CC/8);
  // conv3: bn1, nested input scale, abs-max -> max_h3
  k_conv<<<dim3(127, CB), 256, 0, stream>>>(qT, wl1, g1, b1, m1, v1, hbuf,
      &hdr[2], &hdr[3], 2, &hdrf[6], &hdr[4], 0, T2g, T3g);
  k_quantT<<<dim3(T3g*CW/64, CB), 256, 0, stream>>>(hbuf, qT, &hdr[4], T3g*CW);
  // conv4: bn2, relu-max -> max_r4
  k_conv<<<dim3(126, CB), 256, 0, stream>>>(qT, wl2, g2, b2, m2, v2, hbuf,
      &hdr[4], &hdr[3], 0, &hdrf[7], &hdr[5], 1, T3g, T4g);
  k_final<<<2048, 256, 0, stream>>>(hbuf, (float*)d_out, &hdr[5], CB*CC*T4g*CW/4);
}

// Round 2
// 959.190 us; speedup vs baseline: 1.2769x; 1.2769x over previous
//
#include <hip/hip_runtime.h>
#include <hip/hip_bf16.h>

typedef unsigned int  u32;
typedef unsigned short u16;
typedef unsigned char u8;
typedef __attribute__((ext_vector_type(8))) short  short8;   // 8 bf16 codes (4 VGPRs)
typedef __attribute__((ext_vector_type(8))) u16    ushort8;
typedef __attribute__((ext_vector_type(4))) float  f32x4;

#define DEVI __device__ __forceinline__

constexpr int CB = 16;    // batch
constexpr int CC = 128;   // channels
constexpr int CW = 8;     // width
constexpr int CK = 5;     // kernel taps (dilation 2)
constexpr int T0g = 2048, T1g = 2040, T2g = 2032, T3g = 2024, T4g = 2016;

// ws layout:
//  hdr u32[0]=max_x [1]=max_h1 [2]=max_r2 [3]=qrmax [4]=max_h3 [5]=max_r4 ; f32 [6]=s_w1 [7]=s_w2
//  +512      : wlay1 (5*128*128 bf16 codes, fragment-ordered) 163840 B
//  +512+160K : wlay2
//  +512KiB   : qT   (bf16 codes, [b][n][ci])   67,108,864 B
//  +512K+64M : hbuf (fp32; conv1-3: [b][n][co], conv4: [b][co][n]) 134,217,728 B
//  + ...     : rbuf (u8, [b][n][c])            33,554,432 B

DEVI float wred_max(float m){
  #pragma unroll
  for (int off = 32; off; off >>= 1) m = fmaxf(m, __shfl_down(m, off));
  return m;
}
DEVI u32 wred_maxu(u32 m){
  #pragma unroll
  for (int off = 32; off; off >>= 1){ u32 o = __shfl_down(m, off); m = m > o ? m : o; }
  return m;
}
DEVI float act_scale(u32 bits){ return fmaxf(__uint_as_float(bits) / 127.0f, 1e-8f); }
// exact for small integers (|q|<=255 has >=8 trailing zero mantissa bits)
DEVI u16 f2bf(float q){ return (u16)(__float_as_uint(q) >> 16); }

// ---------------- abs-max over x ----------------
__global__ void k_absmax(const float* __restrict__ x, int n4, u32* __restrict__ slot){
  int gid = blockIdx.x * blockDim.x + threadIdx.x;
  int nth = gridDim.x * blockDim.x;
  const float4* x4 = (const float4*)x;
  float m = 0.f;
  for (int i = gid; i < n4; i += nth){
    float4 v = x4[i];
    m = fmaxf(m, fmaxf(fmaxf(fabsf(v.x), fabsf(v.y)), fmaxf(fabsf(v.z), fabsf(v.w))));
  }
  m = wred_max(m);
  if ((threadIdx.x & 63) == 0 && m > 0.f) atomicMax(slot, __float_as_uint(m));
}

// ---------------- weight quant + fragment-order shuffle ----------------
// wlay linear index = (((kk*4+st)*8 + cot)*64 + lane)*8 + j
//   holds q_w for co = cot*16 + (lane&15), ci = st*32 + (lane>>4)*8 + j  (A-frag order)
__global__ void k_quant_w(const float* __restrict__ w, u16* __restrict__ wlay, float* __restrict__ s_slot){
  __shared__ float red[16];
  int tid = threadIdx.x; // 1024
  float m = 0.f;
  for (int i = tid; i < CC*CC*CK; i += 1024) m = fmaxf(m, fabsf(w[i]));
  m = wred_max(m);
  if ((tid & 63) == 0) red[tid >> 6] = m;
  __syncthreads();
  if (tid == 0){
    float mm = 0.f;
    for (int i = 0; i < 16; i++) mm = fmaxf(mm, red[i]);
    red[0] = fmaxf(mm / 127.0f, 1e-8f);
    *s_slot = red[0];
  }
  __syncthreads();
  float s = red[0];
  for (int i = tid; i < CC*CC*CK; i += 1024){
    int j = i & 7, lane = (i >> 3) & 63, cot = (i >> 9) & 7, st = (i >> 12) & 3, kk = i >> 14;
    int co = cot*16 + (lane & 15), ci = st*32 + (lane >> 4)*8 + j;
    float q = rintf(w[(co*CC + ci)*CK + kk] / s);
    q = fminf(fmaxf(q, -127.f), 127.f);
    wlay[i] = f2bf(q);
  }
}

// ---------------- x: LDS-tiled transpose + quantize  [b][c][N] -> codes [b][n][c] ----------------
__global__ __launch_bounds__(256) void k_qtransX(const float* __restrict__ x, u16* __restrict__ qT,
                          const u32* __restrict__ slot, int N){
  __shared__ float tld[64][65];   // +1 pad: conflict-free column reads
  int b = blockIdx.z, c0 = blockIdx.y * 64, n0 = blockIdx.x * 64;
  float s = act_scale(*slot);
  const float* xb = x + ((size_t)b * CC + c0) * N;
  int tid = threadIdx.x;
  #pragma unroll
  for (int k = 0; k < 4; k++){
    int o = k*256 + tid, r = o >> 4, q = (o & 15) * 4;
    float4 v = *(const float4*)&xb[(size_t)r * N + n0 + q];
    tld[r][q] = v.x; tld[r][q+1] = v.y; tld[r][q+2] = v.z; tld[r][q+3] = v.w;
  }
  __syncthreads();
  u16* qb = qT + (size_t)b * N * CC + c0;
  #pragma unroll
  for (int k = 0; k < 2; k++){
    int o = k*256 + tid, nn = o >> 3, ch = (o & 7) * 8;
    ushort8 pk;
    #pragma unroll
    for (int j = 0; j < 8; j++){
      float q = fminf(fmaxf(rintf(tld[ch+j][nn] / s), -128.f), 127.f);
      pk[j] = f2bf(q);
    }
    *(ushort8*)&qb[(size_t)(n0 + nn) * CC + ch] = pk;
  }
}

// ---------------- elementwise quantize: fp32 [b][n][c] -> codes [b][n][c] ----------------
__global__ void k_quantE(const float* __restrict__ h, u16* __restrict__ qT,
                         const u32* __restrict__ slot, long n8){
  float s = act_scale(*slot);
  long gid = blockIdx.x * (long)blockDim.x + threadIdx.x;
  long nth = (long)gridDim.x * blockDim.x;
  const float4* h4 = (const float4*)h;
  for (long i = gid; i < n8; i += nth){
    float4 a = h4[2*i], c = h4[2*i + 1];
    float vs[8] = {a.x, a.y, a.z, a.w, c.x, c.y, c.z, c.w};
    ushort8 pk;
    #pragma unroll
    for (int j = 0; j < 8; j++){
      float q = fminf(fmaxf(rintf(vs[j] / s), -128.f), 127.f);
      pk[j] = f2bf(q);
    }
    ((ushort8*)qT)[i] = pk;
  }
}

// ---------------- conv + bn (+ fused abs/relu max) ----------------
// qT: [b][n][128] codes. wlay: fragment-ordered codes.
// out_nmajor=1: hout [b][n][co] (float4 stores) ; 0: hout [b][co][n]
// LDS tile: 192 window-rows x 128 ci, chunk-XOR swizzled:
//   physical 16B-chunk p at row n holds logical chunk p^(n&15)  (inverse-swizzled source, rule #21)
__global__ __launch_bounds__(256)
void k_conv(const u16* __restrict__ qT, const u16* __restrict__ wlay,
            const float* __restrict__ gg, const float* __restrict__ bbt,
            const float* __restrict__ mmu, const float* __restrict__ vvar,
            float* __restrict__ hout,
            const u32* __restrict__ slotA, const u32* __restrict__ slotB, int smode,
            const float* __restrict__ sw_slot,
            u32* __restrict__ omax, int relu_mode, int out_nmajor,
            int Tin, int Tout)
{
  __shared__ __align__(16) short lds[192*128];
  __shared__ float s_alpha[CC], s_beta[CC], s_red[4];
  int tid = threadIdx.x;
  int b = blockIdx.y, t0 = blockIdx.x * 16;

  if (tid < CC){
    float inv = gg[tid] / sqrtf(vvar[tid] + 1e-5f);
    float s_in;
    if (smode == 0){
      s_in = act_scale(*slotA);
    } else { // nested: relu-uint8 output re-quantized by quant_act_int8
      float sr = fmaxf(__uint_as_float(*slotA) / 255.0f, 1e-8f);
      float hm = (float)(*slotB) * sr;          // max|h| = q_rmax * s_r
      s_in = fmaxf(hm / 127.0f, 1e-8f);
    }
    s_alpha[tid] = s_in * (*sw_slot) * inv;
    s_beta[tid]  = bbt[tid] - mmu[tid] * inv;
  }

  // stage input window via global_load_lds (width 16), swizzled source
  const u16* qb = qT + (size_t)b * Tin * CW * CC;
  int NT = Tin * CW;
  for (int r = 0; r < 12; r++){
    int ck = r*256 + tid;          // 0..3071
    int n  = ck >> 4;              // window row 0..191
    int p  = ck & 15;              // physical chunk
    int src_n = t0*CW + n;
    if (src_n >= NT) src_n = n & 7;       // tail clamp: any valid row; garbage feeds only invalid cols
    size_t srcoff = (size_t)src_n * CC + (size_t)((p ^ (n & 15)) * 8);
    __builtin_amdgcn_global_load_lds(
        (const __attribute__((address_space(1))) u32*)(qb + srcoff),
        (__attribute__((address_space(3))) u32*)&lds[ck*8], 16, 0, 0);
  }
  __syncthreads();

  int lane = tid & 63, wv = tid >> 6;
  int wr = wv >> 1, wc = wv & 1;           // 2x2 waves: 64co x 64n each
  int l15 = lane & 15, l4 = lane >> 4;

  f32x4 acc[4][4] = {};
  const short8* wb8 = (const short8*)wlay;

  for (int kk = 0; kk < CK; kk++){
    for (int st = 0; st < 4; st++){
      short8 afr[4], bfr[4];
      #pragma unroll
      for (int i = 0; i < 4; i++)
        afr[i] = wb8[((kk*4 + st)*8 + wr*4 + i)*64 + lane];
      #pragma unroll
      for (int i = 0; i < 4; i++){
        int nw  = wc*64 + kk*16 + i*16 + l15;          // window row (n&15 == l15)
        int off = nw*128 + (((st*4 + l4) ^ l15) << 3); // swizzled read, 2-way max (free)
        bfr[i] = *(const short8*)&lds[off];
      }
      #pragma unroll
      for (int i = 0; i < 4; i++)
        #pragma unroll
        for (int j = 0; j < 4; j++)
          acc[i][j] = __builtin_amdgcn_mfma_f32_16x16x32_bf16(afr[i], bfr[j], acc[i][j], 0, 0, 0);
    }
  }

  // epilogue: scale+bn, store, fused max. C/D map: col(n)=lane&15, row(co)=(lane>>4)*4+reg
  float lmax = 0.f;
  int NO = Tout * CW;
  if (out_nmajor){
    float* hb = hout + (size_t)b * NO * CC;
    #pragma unroll
    for (int i = 0; i < 4; i++){
      int co0 = wr*64 + i*16 + l4*4;
      float a0 = s_alpha[co0],   a1 = s_alpha[co0+1], a2 = s_alpha[co0+2], a3 = s_alpha[co0+3];
      float e0 = s_beta[co0],    e1 = s_beta[co0+1],  e2 = s_beta[co0+2],  e3 = s_beta[co0+3];
      #pragma unroll
      for (int j = 0; j < 4; j++){
        int tn = t0*CW + wc*64 + j*16 + l15;
        if (tn < NO){
          float4 v;
          v.x = acc[i][j][0]*a0 + e0; v.y = acc[i][j][1]*a1 + e1;
          v.z = acc[i][j][2]*a2 + e2; v.w = acc[i][j][3]*a3 + e3;
          *(float4*)&hb[(size_t)tn * CC + co0] = v;
          if (relu_mode)
            lmax = fmaxf(lmax, fmaxf(fmaxf(v.x, v.y), fmaxf(v.z, v.w)));
          else
            lmax = fmaxf(lmax, fmaxf(fmaxf(fabsf(v.x), fabsf(v.y)), fmaxf(fabsf(v.z), fabsf(v.w))));
        }
      }
    }
  } else {
    float* hb = hout + (size_t)b * CC * NO;
    #pragma unroll
    for (int i = 0; i < 4; i++){
      #pragma unroll
      for (int j = 0; j < 4; j++){
        int tn = t0*CW + wc*64 + j*16 + l15;
        #pragma unroll
        for (int r2 = 0; r2 < 4; r2++){
          int co = wr*64 + i*16 + l4*4 + r2;
          if (tn < NO){
            float v = acc[i][j][r2] * s_alpha[co] + s_beta[co];
            hb[(size_t)co * NO + tn] = v;
            lmax = fmaxf(lmax, relu_mode ? fmaxf(v, 0.f) : fabsf(v));
          }
        }
      }
    }
  }
  lmax = wred_max(lmax);
  if (lane == 0) s_red[wv] = lmax;
  __syncthreads();
  if (tid == 0){
    float m = fmaxf(fmaxf(s_red[0], s_red[1]), fmaxf(s_red[2], s_red[3]));
    if (m > 0.f) atomicMax(omax, __float_as_uint(m));
  }
}

// ---------------- relu-quant pass A (elementwise): fp32 [b][n][c] -> u8 [b][n][c] + qmax ----------------
__global__ void k_reluE(const float* __restrict__ h, u8* __restrict__ rq,
                        const u32* __restrict__ slotR, u32* __restrict__ qmax_slot, long n16){
  float s = fmaxf(__uint_as_float(*slotR) / 255.0f, 1e-8f);
  long gid = blockIdx.x * (long)blockDim.x + threadIdx.x;
  long nth = (long)gridDim.x * blockDim.x;
  const float4* h4 = (const float4*)h;
  u32 lm = 0;
  for (long i = gid; i < n16; i += nth){
    u8 __attribute__((aligned(16))) pk[16];
    #pragma unroll
    for (int q4 = 0; q4 < 4; q4++){
      float4 v = h4[4*i + q4];
      float vs[4] = {v.x, v.y, v.z, v.w};
      #pragma unroll
      for (int j = 0; j < 4; j++){
        float qv = fminf(fmaxf(rintf(fmaxf(vs[j], 0.f) / s), 0.f), 255.f);
        u32 qi = (u32)qv;
        lm = lm > qi ? lm : qi;
        pk[q4*4 + j] = (u8)qi;
      }
    }
    ((int4*)rq)[i] = *(const int4*)pk;
  }
  lm = wred_maxu(lm);
  if ((threadIdx.x & 63) == 0) atomicMax(qmax_slot, lm);
}

// ---------------- relu-quant pass B: q_r u8 -> nested int8 codes (bf16) ----------------
__global__ void k_passB(const u8* __restrict__ rq, u16* __restrict__ qT,
                        const u32* __restrict__ slotR, const u32* __restrict__ qmax_slot, long n8){
  float sr = fmaxf(__uint_as_float(*slotR) / 255.0f, 1e-8f);
  float s3 = fmaxf(((float)(*qmax_slot) * sr) / 127.0f, 1e-8f);
  long gid = blockIdx.x * (long)blockDim.x + threadIdx.x;
  long nth = (long)gridDim.x * blockDim.x;
  for (long i = gid; i < n8; i += nth){
    uint2 v = ((const uint2*)rq)[i];
    ushort8 pk;
    #pragma unroll
    for (int j = 0; j < 8; j++){
      u32 qr = ((j < 4 ? v.x >> (8*j) : v.y >> (8*(j-4)))) & 0xffu;
      float hv = (float)qr * sr;                     // dequantized relu-uint8 value
      float q  = fminf(fmaxf(rintf(hv / s3), -128.f), 127.f);
      pk[j] = f2bf(q);
    }
    ((ushort8*)qT)[i] = pk;
  }
}

// ---------------- final relu-quant dequantized output (conv4 is c-major -> elementwise) ----------------
__global__ void k_final(const float* __restrict__ h, float* __restrict__ out,
                        const u32* __restrict__ slotR, int n4){
  float s = fmaxf(__uint_as_float(*slotR) / 255.0f, 1e-8f);
  int gid = blockIdx.x * blockDim.x + threadIdx.x;
  int nth = gridDim.x * blockDim.x;
  const float4* h4 = (const float4*)h;
  float4* o4 = (float4*)out;
  for (int i = gid; i < n4; i += nth){
    float4 v = h4[i], r;
    r.x = fminf(fmaxf(rintf(fmaxf(v.x, 0.f) / s), 0.f), 255.f) * s;
    r.y = fminf(fmaxf(rintf(fmaxf(v.y, 0.f) / s), 0.f), 255.f) * s;
    r.z = fminf(fmaxf(rintf(fmaxf(v.z, 0.f) / s), 0.f), 255.f) * s;
    r.w = fminf(fmaxf(rintf(fmaxf(v.w, 0.f) / s), 0.f), 255.f) * s;
    o4[i] = r;
  }
}

extern "C" void kernel_launch(void* const* d_in, const int* in_sizes, int n_in,
                              void* d_out, int out_size, void* d_ws, size_t ws_size,
                              hipStream_t stream){
  const float* x  = (const float*)d_in[0];
  const float* w1 = (const float*)d_in[1];
  const float* w2 = (const float*)d_in[2];
  const float* g1 = (const float*)d_in[3];
  const float* b1 = (const float*)d_in[4];
  const float* m1 = (const float*)d_in[5];
  const float* v1 = (const float*)d_in[6];
  const float* g2 = (const float*)d_in[7];
  const float* b2 = (const float*)d_in[8];
  const float* m2 = (const float*)d_in[9];
  const float* v2 = (const float*)d_in[10];

  char* ws   = (char*)d_ws;
  u32*  hdr  = (u32*)ws;
  float* hdrf = (float*)ws;
  u16* wl1  = (u16*)(ws + 512);
  u16* wl2  = (u16*)(ws + 512 + 163840);
  u16* qT   = (u16*)(ws + (size_t)(1 << 19));
  float* hbuf = (float*)(ws + (size_t)(1 << 19) + (size_t)67108864);
  u8*  rbuf = (u8*)(ws + (size_t)(1 << 19) + (size_t)67108864 + (size_t)134217728);

  hipMemsetAsync(hdr, 0, 64, stream);   // zero max slots (ws is poisoned 0xAA each call)
  k_quant_w<<<1, 1024, 0, stream>>>(w1, wl1, &hdrf[6]);
  k_quant_w<<<1, 1024, 0, stream>>>(w2, wl2, &hdrf[7]);
  k_absmax<<<2048, 256, 0, stream>>>(x, CB*CC*T0g*CW/4, &hdr[0]);
  k_qtransX<<<dim3(T0g*CW/64, 2, CB), 256, 0, stream>>>(x, qT, &hdr[0], T0g*CW);
  // conv1: bn1, abs-max -> max_h1 ; n-major out
  k_conv<<<dim3(128, CB), 256, 0, stream>>>(qT, wl1, g1, b1, m1, v1, hbuf,
      &hdr[0], &hdr[3], 0, &hdrf[6], &hdr[1], 0, 1, T0g, T1g);
  k_quantE<<<2048, 256, 0, stream>>>(hbuf, qT, &hdr[1], (long)CB*T1g*CW*CC/8);
  // conv2: bn2, relu-max -> max_r2 ; n-major out
  k_conv<<<dim3(127, CB), 256, 0, stream>>>(qT, wl2, g2, b2, m2, v2, hbuf,
      &hdr[1], &hdr[3], 0, &hdrf[7], &hdr[2], 1, 1, T1g, T2g);
  k_reluE<<<2048, 256, 0, stream>>>(hbuf, rbuf, &hdr[2], &hdr[3], (long)CB*T2g*CW*CC/16);
  k_passB<<<2048, 256, 0, stream>>>(rbuf, qT, &hdr[2], &hdr[3], (long)CB*T2g*CW*CC/8);
  // conv3: bn1, nested input scale, abs-max -> max_h3 ; n-major out
  k_conv<<<dim3(127, CB), 256, 0, stream>>>(qT, wl1, g1, b1, m1, v1, hbuf,
      &hdr[2], &hdr[3], 2, &hdrf[6], &hdr[4], 0, 1, T2g, T3g);
  k_quantE<<<2048, 256, 0, stream>>>(hbuf, qT, &hdr[4], (long)CB*T3g*CW*CC/8);
  // conv4: bn2, relu-max -> max_r4 ; c-major out (k_final is elementwise in NCHW)
  k_conv<<<dim3(126, CB), 256, 0, stream>>>(qT, wl2, g2, b2, m2, v2, hbuf,
      &hdr[4], &hdr[3], 0, &hdrf[7], &hdr[5], 1, 0, T3g, T4g);
  k_final<<<2048, 256, 0, stream>>>(hbuf, (float*)d_out, &hdr[5], CB*CC*T4g*CW/4);
}

// Round 3
// 772.390 us; speedup vs baseline: 1.5857x; 1.2418x over previous
//
#include <hip/hip_runtime.h>
#include <hip/hip_bf16.h>

typedef unsigned int  u32;
typedef unsigned short u16;
typedef unsigned char u8;
typedef __attribute__((ext_vector_type(8))) short  short8;   // 8 bf16 codes (4 VGPRs)
typedef __attribute__((ext_vector_type(8))) u16    ushort8;
typedef __attribute__((ext_vector_type(4))) float  f32x4;

#define DEVI __device__ __forceinline__

constexpr int CB = 16;    // batch
constexpr int CC = 128;   // channels
constexpr int CW = 8;     // width
constexpr int CK = 5;     // kernel taps (dilation 2)
constexpr int T0g = 2048, T1g = 2040, T2g = 2032, T3g = 2024, T4g = 2016;

// ws layout:
//  hdr u32 slots (8-way each to avoid atomic hotspot):
//    [0..7]=max_x [8..15]=max_h1 [16..23]=max_r2 [24..31]=max_h3 [32..39]=max_r4
//    [40..47]=max_w1 [48..55]=max_w2
//  +512      : wlay1 (5*128*128 bf16 codes, fragment-ordered) 163840 B
//  +512+160K : wlay2
//  +512KiB   : qT   (bf16 codes, [b][n][ci])   67,108,864 B
//  +512K+64M : hbuf (fp32; conv1-3: [b][n][co], conv4: [b][co][n]) 134,217,728 B

DEVI float wred_max(float m){
  #pragma unroll
  for (int off = 32; off; off >>= 1) m = fmaxf(m, __shfl_down(m, off));
  return m;
}
DEVI float slot_max8(const u32* __restrict__ s){
  float m = 0.f;
  #pragma unroll
  for (int i = 0; i < 8; i++) m = fmaxf(m, __uint_as_float(s[i]));
  return m;
}
// exact for small integers (|q|<=255 has >=8 trailing zero mantissa bits)
DEVI u16 f2bf(float q){ return (u16)(__float_as_uint(q) >> 16); }
DEVI float amax4(float4 v){
  return fmaxf(fmaxf(fabsf(v.x), fabsf(v.y)), fmaxf(fabsf(v.z), fabsf(v.w)));
}

// ---------------- abs-max, 4-deep MLP, 8-slot atomics ----------------
__global__ void k_absmax(const float* __restrict__ p, int n4, u32* __restrict__ slots){
  int gid = blockIdx.x * blockDim.x + threadIdx.x;
  int nth = gridDim.x * blockDim.x;
  const float4* p4 = (const float4*)p;
  float m0 = 0.f, m1 = 0.f, m2 = 0.f, m3 = 0.f;
  int i = gid;
  for (; i + 3*nth < n4; i += 4*nth){
    float4 a = p4[i], b = p4[i + nth], c = p4[i + 2*nth], d = p4[i + 3*nth];
    m0 = fmaxf(m0, amax4(a)); m1 = fmaxf(m1, amax4(b));
    m2 = fmaxf(m2, amax4(c)); m3 = fmaxf(m3, amax4(d));
  }
  for (; i < n4; i += nth) m0 = fmaxf(m0, amax4(p4[i]));
  float m = fmaxf(fmaxf(m0, m1), fmaxf(m2, m3));
  m = wred_max(m);
  if ((threadIdx.x & 63) == 0 && m > 0.f) atomicMax(&slots[blockIdx.x & 7], __float_as_uint(m));
}

// ---------------- weight quantize + fragment-order shuffle (parallel) ----------------
// wlay linear index = (((kk*4+st)*8 + cot)*64 + lane)*8 + j
//   holds q_w for co = cot*16 + (lane&15), ci = st*32 + (lane>>4)*8 + j  (A-frag order)
__global__ void k_wshuf(const float* __restrict__ w, u16* __restrict__ wlay,
                        const u32* __restrict__ wm){
  float s = fmaxf(slot_max8(wm) / 127.0f, 1e-8f);
  int t8 = blockIdx.x * 256 + threadIdx.x;       // 40 blocks * 256 * 8 = 81920 exact
  int i0 = t8 * 8;
  int lane = (i0 >> 3) & 63, cot = (i0 >> 9) & 7, st = (i0 >> 12) & 3, kk = i0 >> 14;
  int co = cot*16 + (lane & 15), cib = st*32 + (lane >> 4)*8;
  ushort8 pk;
  #pragma unroll
  for (int j = 0; j < 8; j++){
    float q = rintf(w[(co*CC + cib + j)*CK + kk] / s);
    pk[j] = f2bf(fminf(fmaxf(q, -127.f), 127.f));
  }
  ((ushort8*)wlay)[t8] = pk;
}

// ---------------- x: LDS-tiled transpose + quantize  [b][c][N] -> codes [b][n][c] ----------------
__global__ __launch_bounds__(256) void k_qtransX(const float* __restrict__ x, u16* __restrict__ qT,
                          const u32* __restrict__ slot, int N){
  __shared__ float tld[64][65];   // +1 pad: conflict-free column reads
  int b = blockIdx.z, c0 = blockIdx.y * 64, n0 = blockIdx.x * 64;
  float s = fmaxf(slot_max8(slot) / 127.0f, 1e-8f);
  const float* xb = x + ((size_t)b * CC + c0) * N;
  int tid = threadIdx.x;
  #pragma unroll
  for (int k = 0; k < 4; k++){
    int o = k*256 + tid, r = o >> 4, q = (o & 15) * 4;
    float4 v = *(const float4*)&xb[(size_t)r * N + n0 + q];
    tld[r][q] = v.x; tld[r][q+1] = v.y; tld[r][q+2] = v.z; tld[r][q+3] = v.w;
  }
  __syncthreads();
  u16* qb = qT + (size_t)b * N * CC + c0;
  #pragma unroll
  for (int k = 0; k < 2; k++){
    int o = k*256 + tid, nn = o >> 3, ch = (o & 7) * 8;
    ushort8 pk;
    #pragma unroll
    for (int j = 0; j < 8; j++){
      float q = fminf(fmaxf(rintf(tld[ch+j][nn] / s), -128.f), 127.f);
      pk[j] = f2bf(q);
    }
    *(ushort8*)&qb[(size_t)(n0 + nn) * CC + ch] = pk;
  }
}

// ---------------- elementwise quantize: fp32 [b][n][c] -> codes, 16 elems/iter ----------------
__global__ void k_quantE(const float* __restrict__ h, u16* __restrict__ qT,
                         const u32* __restrict__ slot, long n16){
  float s = fmaxf(slot_max8(slot) / 127.0f, 1e-8f);
  long gid = blockIdx.x * (long)blockDim.x + threadIdx.x;
  long nth = (long)gridDim.x * blockDim.x;
  const float4* h4 = (const float4*)h;
  for (long i = gid; i < n16; i += nth){
    float4 v0 = h4[4*i], v1 = h4[4*i+1], v2 = h4[4*i+2], v3 = h4[4*i+3];
    float vs[16] = {v0.x,v0.y,v0.z,v0.w, v1.x,v1.y,v1.z,v1.w,
                    v2.x,v2.y,v2.z,v2.w, v3.x,v3.y,v3.z,v3.w};
    ushort8 pk0, pk1;
    #pragma unroll
    for (int j = 0; j < 8; j++){
      pk0[j] = f2bf(fminf(fmaxf(rintf(vs[j]   / s), -128.f), 127.f));
      pk1[j] = f2bf(fminf(fmaxf(rintf(vs[j+8] / s), -128.f), 127.f));
    }
    ushort8* dst = (ushort8*)qT + 2*i;
    dst[0] = pk0; dst[1] = pk1;
  }
}

// ---------------- fused relu-uint8 quant + nested int8 requant ----------------
// qmax = clip(round(max_r/s_r),0,255) is achieved at the max element -> analytic (255 in practice)
__global__ void k_reluQ(const float* __restrict__ h, u16* __restrict__ qT,
                        const u32* __restrict__ slotR, long n16){
  float mr = slot_max8(slotR);
  float sr = fmaxf(mr / 255.0f, 1e-8f);
  float qm = fminf(rintf(mr / sr), 255.f);
  float s3 = fmaxf(qm * sr / 127.0f, 1e-8f);
  long gid = blockIdx.x * (long)blockDim.x + threadIdx.x;
  long nth = (long)gridDim.x * blockDim.x;
  const float4* h4 = (const float4*)h;
  for (long i = gid; i < n16; i += nth){
    float4 v0 = h4[4*i], v1 = h4[4*i+1], v2 = h4[4*i+2], v3 = h4[4*i+3];
    float vs[16] = {v0.x,v0.y,v0.z,v0.w, v1.x,v1.y,v1.z,v1.w,
                    v2.x,v2.y,v2.z,v2.w, v3.x,v3.y,v3.z,v3.w};
    ushort8 pk0, pk1;
    #pragma unroll
    for (int j = 0; j < 16; j++){
      float qr = fminf(fmaxf(rintf(fmaxf(vs[j], 0.f) / sr), 0.f), 255.f);
      float hv = qr * sr;                          // dequantized relu-uint8 value (exact product)
      float q3 = fminf(fmaxf(rintf(hv / s3), -128.f), 127.f);
      if (j < 8) pk0[j] = f2bf(q3); else pk1[j-8] = f2bf(q3);
    }
    ushort8* dst = (ushort8*)qT + 2*i;
    dst[0] = pk0; dst[1] = pk1;
  }
}

// ---------------- conv + bn (+ fused abs/relu max) ----------------
// qT: [b][n][128] codes. wlay: fragment-ordered codes.
// K staged in two ci-64 halves -> LDS 24 KiB (6 blocks/CU).
// LDS half-tile: 192 window-rows x 64 ci; 16B chunk p at row n holds logical chunk p^(n&7)
// (inverse-swizzled global source, swizzled read; residual 2-way = free)
__global__ __launch_bounds__(256, 4)
void k_conv(const u16* __restrict__ qT, const u16* __restrict__ wlay,
            const float* __restrict__ gg, const float* __restrict__ bbt,
            const float* __restrict__ mmu, const float* __restrict__ vvar,
            float* __restrict__ hout,
            const u32* __restrict__ slotA, int smode,
            const u32* __restrict__ wm,
            u32* __restrict__ omax, int relu_mode, int out_nmajor,
            int Tin, int Tout)
{
  __shared__ __align__(16) short lds[192*64];
  __shared__ float s_alpha[CC], s_beta[CC], s_red[4];
  int tid = threadIdx.x;
  int b = blockIdx.y, t0 = blockIdx.x * 16;

  if (tid < CC){
    float inv = gg[tid] / sqrtf(vvar[tid] + 1e-5f);
    float mA = slot_max8(slotA);
    float s_in;
    if (smode == 0){
      s_in = fmaxf(mA / 127.0f, 1e-8f);
    } else { // nested: relu-uint8 output re-quantized by quant_act_int8
      float sr = fmaxf(mA / 255.0f, 1e-8f);
      float qm = fminf(rintf(mA / sr), 255.f);
      s_in = fmaxf(qm * sr / 127.0f, 1e-8f);
    }
    float sw = fmaxf(slot_max8(wm) / 127.0f, 1e-8f);
    s_alpha[tid] = s_in * sw * inv;
    s_beta[tid]  = bbt[tid] - mmu[tid] * inv;
  }

  const u16* qb = qT + (size_t)b * Tin * CW * CC;
  int NT = Tin * CW;
  int lane = tid & 63, wv = tid >> 6;
  int wr = wv >> 1, wc = wv & 1;           // 2x2 waves: 64co x 64n each
  int l15 = lane & 15, l4 = lane >> 4;

  f32x4 acc[4][4] = {};
  const short8* wb8 = (const short8*)wlay;

  for (int ph = 0; ph < 2; ph++){
    // stage ci-half ph: 192 rows x 8 chunks of 16B
    for (int r = 0; r < 6; r++){
      int ck = r*256 + tid;          // 0..1535
      int n  = ck >> 3;              // window row
      int p  = ck & 7;               // physical chunk
      int src_n = t0*CW + n;
      if (src_n >= NT) src_n = n & 7;     // tail clamp: garbage feeds only guarded outputs
      size_t srcoff = (size_t)src_n * CC + ph*64 + (size_t)((p ^ (n & 7)) * 8);
      __builtin_amdgcn_global_load_lds(
          (const __attribute__((address_space(1))) u32*)(qb + srcoff),
          (__attribute__((address_space(3))) u32*)&lds[ck*8], 16, 0, 0);
    }
    __syncthreads();
    for (int kk = 0; kk < CK; kk++){
      #pragma unroll
      for (int stl = 0; stl < 2; stl++){
        int st = ph*2 + stl;
        short8 afr[4], bfr[4];
        #pragma unroll
        for (int i = 0; i < 4; i++)
          afr[i] = wb8[((kk*4 + st)*8 + wr*4 + i)*64 + lane];
        #pragma unroll
        for (int i = 0; i < 4; i++){
          int nw  = wc*64 + kk*16 + i*16 + l15;
          int off = nw*64 + (((stl*4 + l4) ^ (l15 & 7)) << 3);
          bfr[i] = *(const short8*)&lds[off];
        }
        #pragma unroll
        for (int i = 0; i < 4; i++)
          #pragma unroll
          for (int j = 0; j < 4; j++)
            acc[i][j] = __builtin_amdgcn_mfma_f32_16x16x32_bf16(afr[i], bfr[j], acc[i][j], 0, 0, 0);
      }
    }
    __syncthreads();   // WAR: don't overwrite LDS until all waves done with it
  }

  // epilogue. C/D map: col(n)=lane&15, row(co)=(lane>>4)*4+reg
  float lmax = 0.f;
  int NO = Tout * CW;
  if (out_nmajor){
    float* hb = hout + (size_t)b * NO * CC;
    #pragma unroll
    for (int i = 0; i < 4; i++){
      int co0 = wr*64 + i*16 + l4*4;
      float a0 = s_alpha[co0],   a1 = s_alpha[co0+1], a2 = s_alpha[co0+2], a3 = s_alpha[co0+3];
      float e0 = s_beta[co0],    e1 = s_beta[co0+1],  e2 = s_beta[co0+2],  e3 = s_beta[co0+3];
      #pragma unroll
      for (int j = 0; j < 4; j++){
        int tn = t0*CW + wc*64 + j*16 + l15;
        if (tn < NO){
          float4 v;
          v.x = acc[i][j][0]*a0 + e0; v.y = acc[i][j][1]*a1 + e1;
          v.z = acc[i][j][2]*a2 + e2; v.w = acc[i][j][3]*a3 + e3;
          *(float4*)&hb[(size_t)tn * CC + co0] = v;
          if (relu_mode)
            lmax = fmaxf(lmax, fmaxf(fmaxf(v.x, v.y), fmaxf(v.z, v.w)));
          else
            lmax = fmaxf(lmax, fmaxf(fmaxf(fabsf(v.x), fabsf(v.y)), fmaxf(fabsf(v.z), fabsf(v.w))));
        }
      }
    }
  } else {
    float* hb = hout + (size_t)b * CC * NO;
    #pragma unroll
    for (int i = 0; i < 4; i++){
      #pragma unroll
      for (int j = 0; j < 4; j++){
        int tn = t0*CW + wc*64 + j*16 + l15;
        #pragma unroll
        for (int r2 = 0; r2 < 4; r2++){
          int co = wr*64 + i*16 + l4*4 + r2;
          if (tn < NO){
            float v = acc[i][j][r2] * s_alpha[co] + s_beta[co];
            hb[(size_t)co * NO + tn] = v;
            lmax = fmaxf(lmax, relu_mode ? fmaxf(v, 0.f) : fabsf(v));
          }
        }
      }
    }
  }
  lmax = wred_max(lmax);
  if (lane == 0) s_red[wv] = lmax;
  __syncthreads();
  if (tid == 0){
    float m = fmaxf(fmaxf(s_red[0], s_red[1]), fmaxf(s_red[2], s_red[3]));
    if (m > 0.f) atomicMax(&omax[blockIdx.x & 7], __float_as_uint(m));
  }
}

// ---------------- final relu-quant dequantized output (conv4 c-major -> elementwise) ----------------
__global__ void k_final(const float* __restrict__ h, float* __restrict__ out,
                        const u32* __restrict__ slotR, long n8){
  float s = fmaxf(slot_max8(slotR) / 255.0f, 1e-8f);
  long gid = blockIdx.x * (long)blockDim.x + threadIdx.x;
  long nth = (long)gridDim.x * blockDim.x;
  const float4* h4 = (const float4*)h;
  float4* o4 = (float4*)out;
  for (long i = gid; i < n8; i += nth){
    float4 v0 = h4[2*i], v1 = h4[2*i+1], r0, r1;
    r0.x = fminf(fmaxf(rintf(fmaxf(v0.x, 0.f) / s), 0.f), 255.f) * s;
    r0.y = fminf(fmaxf(rintf(fmaxf(v0.y, 0.f) / s), 0.f), 255.f) * s;
    r0.z = fminf(fmaxf(rintf(fmaxf(v0.z, 0.f) / s), 0.f), 255.f) * s;
    r0.w = fminf(fmaxf(rintf(fmaxf(v0.w, 0.f) / s), 0.f), 255.f) * s;
    r1.x = fminf(fmaxf(rintf(fmaxf(v1.x, 0.f) / s), 0.f), 255.f) * s;
    r1.y = fminf(fmaxf(rintf(fmaxf(v1.y, 0.f) / s), 0.f), 255.f) * s;
    r1.z = fminf(fmaxf(rintf(fmaxf(v1.z, 0.f) / s), 0.f), 255.f) * s;
    r1.w = fminf(fmaxf(rintf(fmaxf(v1.w, 0.f) / s), 0.f), 255.f) * s;
    o4[2*i] = r0; o4[2*i+1] = r1;
  }
}

extern "C" void kernel_launch(void* const* d_in, const int* in_sizes, int n_in,
                              void* d_out, int out_size, void* d_ws, size_t ws_size,
                              hipStream_t stream){
  const float* x  = (const float*)d_in[0];
  const float* w1 = (const float*)d_in[1];
  const float* w2 = (const float*)d_in[2];
  const float* g1 = (const float*)d_in[3];
  const float* b1 = (const float*)d_in[4];
  const float* m1 = (const float*)d_in[5];
  const float* v1 = (const float*)d_in[6];
  const float* g2 = (const float*)d_in[7];
  const float* b2 = (const float*)d_in[8];
  const float* m2 = (const float*)d_in[9];
  const float* v2 = (const float*)d_in[10];

  char* ws   = (char*)d_ws;
  u32*  hdr  = (u32*)ws;
  u16* wl1  = (u16*)(ws + 512);
  u16* wl2  = (u16*)(ws + 512 + 163840);
  u16* qT   = (u16*)(ws + (size_t)(1 << 19));
  float* hbuf = (float*)(ws + (size_t)(1 << 19) + (size_t)67108864);

  hipMemsetAsync(hdr, 0, 256, stream);
  k_absmax<<<20, 256, 0, stream>>>(w1, CC*CC*CK/4, &hdr[40]);
  k_absmax<<<20, 256, 0, stream>>>(w2, CC*CC*CK/4, &hdr[48]);
  k_wshuf<<<40, 256, 0, stream>>>(w1, wl1, &hdr[40]);
  k_wshuf<<<40, 256, 0, stream>>>(w2, wl2, &hdr[48]);
  k_absmax<<<1024, 256, 0, stream>>>(x, CB*CC*T0g*CW/4, &hdr[0]);
  k_qtransX<<<dim3(T0g*CW/64, 2, CB), 256, 0, stream>>>(x, qT, &hdr[0], T0g*CW);
  // conv1: bn1, abs-max -> max_h1 ; n-major out
  k_conv<<<dim3(128, CB), 256, 0, stream>>>(qT, wl1, g1, b1, m1, v1, hbuf,
      &hdr[0], 0, &hdr[40], &hdr[8], 0, 1, T0g, T1g);
  k_quantE<<<1024, 256, 0, stream>>>(hbuf, qT, &hdr[8], (long)CB*T1g*CW*CC/16);
  // conv2: bn2, relu-max -> max_r2 ; n-major out
  k_conv<<<dim3(127, CB), 256, 0, stream>>>(qT, wl2, g2, b2, m2, v2, hbuf,
      &hdr[8], 0, &hdr[48], &hdr[16], 1, 1, T1g, T2g);
  // fused relu-uint8 + nested int8 requant (qmax analytic)
  k_reluQ<<<1024, 256, 0, stream>>>(hbuf, qT, &hdr[16], (long)CB*T2g*CW*CC/16);
  // conv3: bn1, nested input scale, abs-max -> max_h3 ; n-major out
  k_conv<<<dim3(127, CB), 256, 0, stream>>>(qT, wl1, g1, b1, m1, v1, hbuf,
      &hdr[16], 1, &hdr[40], &hdr[24], 0, 1, T2g, T3g);
  k_quantE<<<1024, 256, 0, stream>>>(hbuf, qT, &hdr[24], (long)CB*T3g*CW*CC/16);
  // conv4: bn2, relu-max -> max_r4 ; c-major out (k_final is elementwise in NCHW)
  k_conv<<<dim3(126, CB), 256, 0, stream>>>(qT, wl2, g2, b2, m2, v2, hbuf,
      &hdr[24], 0, &hdr[48], &hdr[32], 1, 0, T3g, T4g);
  k_final<<<1024, 256, 0, stream>>>(hbuf, (float*)d_out, &hdr[32], (long)CB*CC*T4g*CW/8);
}

// Round 4
// 636.041 us; speedup vs baseline: 1.9256x; 1.2144x over previous
//
#include <hip/hip_runtime.h>
#include <hip/hip_bf16.h>

typedef unsigned int  u32;
typedef unsigned short u16;
typedef unsigned char u8;
typedef __attribute__((ext_vector_type(4))) int i32x4;

#define DEVI __device__ __forceinline__

constexpr int CB = 16;    // batch
constexpr int CC = 128;   // channels
constexpr int CW = 8;     // width
constexpr int CK = 5;     // kernel taps (dilation 2)
constexpr int T0g = 2048, T1g = 2040, T2g = 2032, T3g = 2024, T4g = 2016;

// ws layout:
//  hdr u32 slots (8-way each): [0..7]=max_x [8..15]=max_h1 [16..23]=max_r2
//    [24..31]=max_h3 [32..39]=max_r4 [40..47]=max_w1 [48..55]=max_w2
//  +512       : wlay1 (int8 codes, fragment-ordered) 81,920 B
//  +512+80K   : wlay2
//  +256KiB    : qT   (int8 codes, [b][n][128])  33,554,432 B
//  +256K+32M  : hbuf (fp32; conv1-3: [b][n][co], conv4: [b][co][n]) 134,217,728 B

DEVI float wred_max(float m){
  #pragma unroll
  for (int off = 32; off; off >>= 1) m = fmaxf(m, __shfl_down(m, off));
  return m;
}
DEVI float slot_max8(const u32* __restrict__ s){
  float m = 0.f;
  #pragma unroll
  for (int i = 0; i < 8; i++) m = fmaxf(m, __uint_as_float(s[i]));
  return m;
}
DEVI float amax4(float4 v){
  return fmaxf(fmaxf(fabsf(v.x), fabsf(v.y)), fmaxf(fabsf(v.z), fabsf(v.w)));
}

// ---------------- abs-max, 4-deep MLP, 8-slot atomics ----------------
__global__ void k_absmax(const float* __restrict__ p, int n4, u32* __restrict__ slots){
  int gid = blockIdx.x * blockDim.x + threadIdx.x;
  int nth = gridDim.x * blockDim.x;
  const float4* p4 = (const float4*)p;
  float m0 = 0.f, m1 = 0.f, m2 = 0.f, m3 = 0.f;
  int i = gid;
  for (; i + 3*nth < n4; i += 4*nth){
    float4 a = p4[i], b = p4[i + nth], c = p4[i + 2*nth], d = p4[i + 3*nth];
    m0 = fmaxf(m0, amax4(a)); m1 = fmaxf(m1, amax4(b));
    m2 = fmaxf(m2, amax4(c)); m3 = fmaxf(m3, amax4(d));
  }
  for (; i < n4; i += nth) m0 = fmaxf(m0, amax4(p4[i]));
  float m = fmaxf(fmaxf(m0, m1), fmaxf(m2, m3));
  m = wred_max(m);
  if ((threadIdx.x & 63) == 0 && m > 0.f) atomicMax(&slots[blockIdx.x & 7], __float_as_uint(m));
}

// ---------------- weight quantize + fragment-order shuffle (int8) ----------------
// 16B-unit t = ((kk*2+ks)*8 + cot)*64 + lane ; byte j of t:
//   co = cot*16 + (lane&15), ci = ks*64 + (lane>>4)*16 + j   (A-frag for 16x16x64 i8)
__global__ void k_wshuf(const float* __restrict__ w, char* __restrict__ wlay,
                        const u32* __restrict__ wm){
  float s = fmaxf(slot_max8(wm) / 127.0f, 1e-8f);
  int t = blockIdx.x * 256 + threadIdx.x;        // 20 blocks * 256 = 5120 = 81920/16
  int lane = t & 63, cot = (t >> 6) & 7, ks = (t >> 9) & 1, kk = t >> 10;
  int co = cot*16 + (lane & 15), cib = ks*64 + (lane >> 4)*16;
  char __attribute__((aligned(16))) pk[16];
  #pragma unroll
  for (int j = 0; j < 16; j++){
    float q = rintf(w[(co*CC + cib + j)*CK + kk] / s);
    pk[j] = (char)fminf(fmaxf(q, -127.f), 127.f);
  }
  ((int4*)wlay)[t] = *(const int4*)pk;
}

// ---------------- x: LDS-tiled transpose + quantize  [b][c][N] -> int8 [b][n][c] ----------------
__global__ __launch_bounds__(256) void k_qtransX(const float* __restrict__ x, char* __restrict__ qT,
                          const u32* __restrict__ slot, int N){
  __shared__ float tld[64][65];   // +1 pad: conflict-free column reads
  int b = blockIdx.z, c0 = blockIdx.y * 64, n0 = blockIdx.x * 64;
  float s = fmaxf(slot_max8(slot) / 127.0f, 1e-8f);
  const float* xb = x + ((size_t)b * CC + c0) * N;
  int tid = threadIdx.x;
  #pragma unroll
  for (int k = 0; k < 4; k++){
    int o = k*256 + tid, r = o >> 4, q = (o & 15) * 4;
    float4 v = *(const float4*)&xb[(size_t)r * N + n0 + q];
    tld[r][q] = v.x; tld[r][q+1] = v.y; tld[r][q+2] = v.z; tld[r][q+3] = v.w;
  }
  __syncthreads();
  char* qb = qT + (size_t)b * N * CC + c0;
  int nn = tid >> 2, ch = (tid & 3) * 16;
  char __attribute__((aligned(16))) pk[16];
  #pragma unroll
  for (int j = 0; j < 16; j++){
    float q = fminf(fmaxf(rintf(tld[ch+j][nn] / s), -128.f), 127.f);
    pk[j] = (char)q;
  }
  *(int4*)&qb[(size_t)(n0 + nn) * CC + ch] = *(const int4*)pk;
}

// ---------------- elementwise quantize: fp32 [b][n][c] -> int8, 16 elems/iter ----------------
__global__ void k_quantE(const float* __restrict__ h, char* __restrict__ qT,
                         const u32* __restrict__ slot, long n16){
  float s = fmaxf(slot_max8(slot) / 127.0f, 1e-8f);
  long gid = blockIdx.x * (long)blockDim.x + threadIdx.x;
  long nth = (long)gridDim.x * blockDim.x;
  const float4* h4 = (const float4*)h;
  for (long i = gid; i < n16; i += nth){
    float4 v0 = h4[4*i], v1 = h4[4*i+1], v2 = h4[4*i+2], v3 = h4[4*i+3];
    float vs[16] = {v0.x,v0.y,v0.z,v0.w, v1.x,v1.y,v1.z,v1.w,
                    v2.x,v2.y,v2.z,v2.w, v3.x,v3.y,v3.z,v3.w};
    char __attribute__((aligned(16))) pk[16];
    #pragma unroll
    for (int j = 0; j < 16; j++)
      pk[j] = (char)fminf(fmaxf(rintf(vs[j] / s), -128.f), 127.f);
    ((int4*)qT)[i] = *(const int4*)pk;
  }
}

// ---------------- fused relu-uint8 quant + nested int8 requant ----------------
__global__ void k_reluQ(const float* __restrict__ h, char* __restrict__ qT,
                        const u32* __restrict__ slotR, long n16){
  float mr = slot_max8(slotR);
  float sr = fmaxf(mr / 255.0f, 1e-8f);
  float qm = fminf(rintf(mr / sr), 255.f);
  float s3 = fmaxf(qm * sr / 127.0f, 1e-8f);
  long gid = blockIdx.x * (long)blockDim.x + threadIdx.x;
  long nth = (long)gridDim.x * blockDim.x;
  const float4* h4 = (const float4*)h;
  for (long i = gid; i < n16; i += nth){
    float4 v0 = h4[4*i], v1 = h4[4*i+1], v2 = h4[4*i+2], v3 = h4[4*i+3];
    float vs[16] = {v0.x,v0.y,v0.z,v0.w, v1.x,v1.y,v1.z,v1.w,
                    v2.x,v2.y,v2.z,v2.w, v3.x,v3.y,v3.z,v3.w};
    char __attribute__((aligned(16))) pk[16];
    #pragma unroll
    for (int j = 0; j < 16; j++){
      float qr = fminf(fmaxf(rintf(fmaxf(vs[j], 0.f) / sr), 0.f), 255.f);
      float hv = qr * sr;                          // exact dequantized relu-uint8
      pk[j] = (char)fminf(fmaxf(rintf(hv / s3), -128.f), 127.f);
    }
    ((int4*)qT)[i] = *(const int4*)pk;
  }
}

// ---------------- conv + bn (+ fused abs/relu max), int8 MFMA core ----------------
// qT: [b][n][128] int8. wlay: fragment-ordered int8.
// LDS: 192 rows x 128 B, one stage per block. 16B chunk p at row n holds logical chunk p^(n&7)
// (inverse-swizzled global source, swizzled read; balanced 8-lanes/4-bank group = conflict-free)
__global__ __launch_bounds__(256)
void k_conv(const char* __restrict__ qT, const char* __restrict__ wlay,
            const float* __restrict__ gg, const float* __restrict__ bbt,
            const float* __restrict__ mmu, const float* __restrict__ vvar,
            float* __restrict__ hout,
            const u32* __restrict__ slotA, int smode,
            const u32* __restrict__ wm,
            u32* __restrict__ omax, int relu_mode, int out_nmajor,
            int Tin, int Tout)
{
  __shared__ __align__(16) char lds8[192*128];
  __shared__ float s_alpha[CC], s_beta[CC], s_red[4];
  int tid = threadIdx.x;
  int b = blockIdx.y, t0 = blockIdx.x * 16;

  // stage input window first (latency overlaps scale setup below)
  const char* qb = qT + (size_t)b * Tin * CW * CC;
  int NT = Tin * CW;
  for (int r = 0; r < 6; r++){
    int ck = r*256 + tid;          // 0..1535 chunks of 16B
    int n  = ck >> 3;              // LDS row 0..191
    int p  = ck & 7;               // physical chunk
    int src_n = t0*CW + n;
    if (src_n >= NT) src_n = n & 7;     // tail clamp: garbage feeds only guarded outputs
    size_t so = (size_t)src_n * CC + (size_t)((p ^ (n & 7)) << 4);
    __builtin_amdgcn_global_load_lds(
        (const __attribute__((address_space(1))) u32*)(qb + so),
        (__attribute__((address_space(3))) u32*)&lds8[ck*16], 16, 0, 0);
  }

  if (tid < CC){
    float inv = gg[tid] / sqrtf(vvar[tid] + 1e-5f);
    float mA = slot_max8(slotA);
    float s_in;
    if (smode == 0){
      s_in = fmaxf(mA / 127.0f, 1e-8f);
    } else { // nested: relu-uint8 output re-quantized by quant_act_int8
      float sr = fmaxf(mA / 255.0f, 1e-8f);
      float qm = fminf(rintf(mA / sr), 255.f);
      s_in = fmaxf(qm * sr / 127.0f, 1e-8f);
    }
    float sw = fmaxf(slot_max8(wm) / 127.0f, 1e-8f);
    s_alpha[tid] = s_in * sw * inv;
    s_beta[tid]  = bbt[tid] - mmu[tid] * inv;
  }
  __syncthreads();

  int lane = tid & 63, wv = tid >> 6;
  int wr = wv >> 1, wc = wv & 1;           // 2x2 waves: 64co x 64n each
  int l15 = lane & 15, l4 = lane >> 4;

  i32x4 acc[4][4] = {};
  const i32x4* wA = (const i32x4*)wlay;

  #pragma unroll
  for (int s = 0; s < 10; s++){            // s = kk*2 + ks (5 taps x 2 ci-halves)
    int kk = s >> 1, ks = s & 1;
    i32x4 af[4], bf[4];
    #pragma unroll
    for (int i = 0; i < 4; i++)
      af[i] = wA[(s*8 + wr*4 + i)*64 + lane];
    #pragma unroll
    for (int j = 0; j < 4; j++){
      int nw  = wc*64 + kk*16 + j*16 + l15;            // window row; nw&7 == l15&7
      int off = nw*128 + (((ks*4 + l4) ^ (l15 & 7)) << 4);
      bf[j] = *(const i32x4*)&lds8[off];
    }
    #pragma unroll
    for (int i = 0; i < 4; i++)
      #pragma unroll
      for (int j = 0; j < 4; j++)
        acc[i][j] = __builtin_amdgcn_mfma_i32_16x16x64_i8(af[i], bf[j], acc[i][j], 0, 0, 0);
  }

  // epilogue. C/D map: col(n)=lane&15, row(co)=(lane>>4)*4+reg
  float lmax = 0.f;
  int NO = Tout * CW;
  if (out_nmajor){
    float* hb = hout + (size_t)b * NO * CC;
    #pragma unroll
    for (int i = 0; i < 4; i++){
      int co0 = wr*64 + i*16 + l4*4;
      float a0 = s_alpha[co0],   a1 = s_alpha[co0+1], a2 = s_alpha[co0+2], a3 = s_alpha[co0+3];
      float e0 = s_beta[co0],    e1 = s_beta[co0+1],  e2 = s_beta[co0+2],  e3 = s_beta[co0+3];
      #pragma unroll
      for (int j = 0; j < 4; j++){
        int tn = t0*CW + wc*64 + j*16 + l15;
        if (tn < NO){
          float4 v;
          v.x = (float)acc[i][j][0]*a0 + e0; v.y = (float)acc[i][j][1]*a1 + e1;
          v.z = (float)acc[i][j][2]*a2 + e2; v.w = (float)acc[i][j][3]*a3 + e3;
          *(float4*)&hb[(size_t)tn * CC + co0] = v;
          if (relu_mode)
            lmax = fmaxf(lmax, fmaxf(fmaxf(v.x, v.y), fmaxf(v.z, v.w)));
          else
            lmax = fmaxf(lmax, fmaxf(fmaxf(fabsf(v.x), fabsf(v.y)), fmaxf(fabsf(v.z), fabsf(v.w))));
        }
      }
    }
  } else {
    float* hb = hout + (size_t)b * CC * NO;
    #pragma unroll
    for (int i = 0; i < 4; i++){
      #pragma unroll
      for (int j = 0; j < 4; j++){
        int tn = t0*CW + wc*64 + j*16 + l15;
        #pragma unroll
        for (int r2 = 0; r2 < 4; r2++){
          int co = wr*64 + i*16 + l4*4 + r2;
          if (tn < NO){
            float v = (float)acc[i][j][r2] * s_alpha[co] + s_beta[co];
            hb[(size_t)co * NO + tn] = v;
            lmax = fmaxf(lmax, relu_mode ? fmaxf(v, 0.f) : fabsf(v));
          }
        }
      }
    }
  }
  lmax = wred_max(lmax);
  if (lane == 0) s_red[wv] = lmax;
  __syncthreads();
  if (tid == 0){
    float m = fmaxf(fmaxf(s_red[0], s_red[1]), fmaxf(s_red[2], s_red[3]));
    if (m > 0.f) atomicMax(&omax[blockIdx.x & 7], __float_as_uint(m));
  }
}

// ---------------- final relu-quant dequantized output (conv4 c-major -> elementwise) ----------------
__global__ void k_final(const float* __restrict__ h, float* __restrict__ out,
                        const u32* __restrict__ slotR, long n8){
  float s = fmaxf(slot_max8(slotR) / 255.0f, 1e-8f);
  long gid = blockIdx.x * (long)blockDim.x + threadIdx.x;
  long nth = (long)gridDim.x * blockDim.x;
  const float4* h4 = (const float4*)h;
  float4* o4 = (float4*)out;
  for (long i = gid; i < n8; i += nth){
    float4 v0 = h4[2*i], v1 = h4[2*i+1], r0, r1;
    r0.x = fminf(fmaxf(rintf(fmaxf(v0.x, 0.f) / s), 0.f), 255.f) * s;
    r0.y = fminf(fmaxf(rintf(fmaxf(v0.y, 0.f) / s), 0.f), 255.f) * s;
    r0.z = fminf(fmaxf(rintf(fmaxf(v0.z, 0.f) / s), 0.f), 255.f) * s;
    r0.w = fminf(fmaxf(rintf(fmaxf(v0.w, 0.f) / s), 0.f), 255.f) * s;
    r1.x = fminf(fmaxf(rintf(fmaxf(v1.x, 0.f) / s), 0.f), 255.f) * s;
    r1.y = fminf(fmaxf(rintf(fmaxf(v1.y, 0.f) / s), 0.f), 255.f) * s;
    r1.z = fminf(fmaxf(rintf(fmaxf(v1.z, 0.f) / s), 0.f), 255.f) * s;
    r1.w = fminf(fmaxf(rintf(fmaxf(v1.w, 0.f) / s), 0.f), 255.f) * s;
    o4[2*i] = r0; o4[2*i+1] = r1;
  }
}

extern "C" void kernel_launch(void* const* d_in, const int* in_sizes, int n_in,
                              void* d_out, int out_size, void* d_ws, size_t ws_size,
                              hipStream_t stream){
  const float* x  = (const float*)d_in[0];
  const float* w1 = (const float*)d_in[1];
  const float* w2 = (const float*)d_in[2];
  const float* g1 = (const float*)d_in[3];
  const float* b1 = (const float*)d_in[4];
  const float* m1 = (const float*)d_in[5];
  const float* v1 = (const float*)d_in[6];
  const float* g2 = (const float*)d_in[7];
  const float* b2 = (const float*)d_in[8];
  const float* m2 = (const float*)d_in[9];
  const float* v2 = (const float*)d_in[10];

  char* ws   = (char*)d_ws;
  u32*  hdr  = (u32*)ws;
  char* wl1  = ws + 512;
  char* wl2  = ws + 512 + 81920;
  char* qT   = ws + (size_t)(1 << 18);
  float* hbuf = (float*)(ws + (size_t)(1 << 18) + (size_t)33554432);

  hipMemsetAsync(hdr, 0, 256, stream);
  k_absmax<<<20, 256, 0, stream>>>(w1, CC*CC*CK/4, &hdr[40]);
  k_absmax<<<20, 256, 0, stream>>>(w2, CC*CC*CK/4, &hdr[48]);
  k_wshuf<<<20, 256, 0, stream>>>(w1, wl1, &hdr[40]);
  k_wshuf<<<20, 256, 0, stream>>>(w2, wl2, &hdr[48]);
  k_absmax<<<1024, 256, 0, stream>>>(x, CB*CC*T0g*CW/4, &hdr[0]);
  k_qtransX<<<dim3(T0g*CW/64, 2, CB), 256, 0, stream>>>(x, qT, &hdr[0], T0g*CW);
  // conv1: bn1, abs-max -> max_h1 ; n-major out
  k_conv<<<dim3(128, CB), 256, 0, stream>>>(qT, wl1, g1, b1, m1, v1, hbuf,
      &hdr[0], 0, &hdr[40], &hdr[8], 0, 1, T0g, T1g);
  k_quantE<<<1024, 256, 0, stream>>>(hbuf, qT, &hdr[8], (long)CB*T1g*CW*CC/16);
  // conv2: bn2, relu-max -> max_r2 ; n-major out
  k_conv<<<dim3(127, CB), 256, 0, stream>>>(qT, wl2, g2, b2, m2, v2, hbuf,
      &hdr[8], 0, &hdr[48], &hdr[16], 1, 1, T1g, T2g);
  // fused relu-uint8 + nested int8 requant (qmax analytic)
  k_reluQ<<<1024, 256, 0, stream>>>(hbuf, qT, &hdr[16], (long)CB*T2g*CW*CC/16);
  // conv3: bn1, nested input scale, abs-max -> max_h3 ; n-major out
  k_conv<<<dim3(127, CB), 256, 0, stream>>>(qT, wl1, g1, b1, m1, v1, hbuf,
      &hdr[16], 1, &hdr[40], &hdr[24], 0, 1, T2g, T3g);
  k_quantE<<<1024, 256, 0, stream>>>(hbuf, qT, &hdr[24], (long)CB*T3g*CW*CC/16);
  // conv4: bn2, relu-max -> max_r4 ; c-major out (k_final is elementwise in NCHW)
  k_conv<<<dim3(126, CB), 256, 0, stream>>>(qT, wl2, g2, b2, m2, v2, hbuf,
      &hdr[24], 0, &hdr[48], &hdr[32], 1, 0, T3g, T4g);
  k_final<<<1024, 256, 0, stream>>>(hbuf, (float*)d_out, &hdr[32], (long)CB*CC*T4g*CW/8);
}